// Round 5
// baseline (1031.298 us; speedup 1.0000x reference)
//
#include <hip/hip_runtime.h>
#include <hip/hip_bf16.h>

#define BB 32
#define NN 128
#define EE 16384
#define ROWS_E (BB*EE)     // 524288
#define ROWS_N (BB*NN)     // 4096
#define EPS_BN 1e-5f

// d_out layout (floats): h_out, x_out, m
#define XOUT_OFF (ROWS_N*72)
#define M_OFF    (XOUT_OFF + ROWS_N*4)

// ws layout (floats)
#define ST1_OFF 0            // sum[72], sq[72], mean@144, inv@216, S@288, T@360
#define ST2_OFF 512
#define AGG_OFF 1024
#define CNT_OFF (AGG_OFF + ROWS_N*4)       // 17408
#define MAGG_OFF (CNT_OFF + ROWS_N)        // 21504
#define Z2_OFF (MAGG_OFF + ROWS_N*72)      // 316416
#define ZERO_FLOATS Z2_OFF                 // zero [0, Z2_OFF)
#define G2_OFF (Z2_OFF + ROWS_N*72)        // 611328
#define WSW_OFF (G2_OFF + ROWS_E)          // 1135616
#define Z1BF_OFF (WSW_OFF + 24320)         // 1159936
// total floats: 1159936 + 9437184 = 10597120 (~42.4 MB) — ws proven >= 78 MB in R4

// swizzled bf16 weight fragments (ushort offsets): entry ((kc*5+mt)*64+lane)*8+t
#define W1SW 0          // kc=5, K=146->160 : 12800
#define W2SW 12800      // kc=3, K=72->96   : 7680
#define W3SW 20480      // kc=3             : 7680
#define WH1SW 28160     // kc=5, K=148->160 : 12800
#define WH2SW 40960     // kc=3             : 7680
#define WSW_TOTAL 48640

typedef __attribute__((ext_vector_type(8))) short short8;
typedef __attribute__((ext_vector_type(4))) float f32x4;

__device__ __forceinline__ float psi_f(float p) {
    return copysignf(log1pf(fabsf(p)), p);
}
__device__ __forceinline__ unsigned short f2bf(float f) {
    union { float f; unsigned u; } v; v.f = f;
    unsigned r = v.u + 0x7fffu + ((v.u >> 16) & 1u);
    return (unsigned short)(r >> 16);
}
__device__ __forceinline__ unsigned pk(float a, float b) {
    union { __hip_bfloat162 h; unsigned u; } cv;
    cv.h = __float22bfloat162_rn(make_float2(a, b));
    return cv.u;
}
__device__ __forceinline__ float bfu2f(unsigned u) {  // low 16 bits = bf16
    union { unsigned u; float f; } v; v.u = u << 16; return v.f;
}

// ---------- weight prep: swizzled fragment layout, coalesced at use site
__global__ void k_prep(const float* __restrict__ We1, const float* __restrict__ We2,
                       const float* __restrict__ Wx1, const float* __restrict__ Wh1,
                       const float* __restrict__ Wh2, unsigned short* __restrict__ wsw)
{
    int idx = blockIdx.x * 256 + threadIdx.x;
    if (idx >= WSW_TOTAL) return;
    const float* src; int off = idx, K;
    if (idx < W2SW)       {               src = We1; K = 146; }
    else if (idx < W3SW)  { off -= W2SW;  src = We2; K = 72; }
    else if (idx < WH1SW) { off -= W3SW;  src = Wx1; K = 72; }
    else if (idx < WH2SW) { off -= WH1SW; src = Wh1; K = 148; }
    else                  { off -= WH2SW; src = Wh2; K = 72; }
    int t = off & 7;
    int lane = (off >> 3) & 63;
    int fg = off >> 9;                 // kc*5 + mt
    int mt = fg % 5, kc = fg / 5;
    int c = lane & 15, quad = lane >> 4;
    int mcol = mt * 16 + c;
    int k = kc * 32 + quad * 8 + t;
    wsw[idx] = (mcol < 72 && k < K) ? f2bf(src[k * 72 + mcol]) : (unsigned short)0;
}

// ---------- GEMM1: z1[e][col] bf16 ; A=We1 frags (coalesced), B=edge rows from LDS-staged h
__global__ __launch_bounds__(256, 4) void k_edge_gemm1(
    const float* __restrict__ h, const float* __restrict__ x,
    const int* __restrict__ ei, const int* __restrict__ ej,
    const unsigned short* __restrict__ wsw, unsigned short* __restrict__ z1bf)
{
    __shared__ unsigned short hb[128 * 72];     // batch h, bf16
    __shared__ float xs[128 * 4];
    __shared__ unsigned short ztile[4][32 * 72];
    int tid = threadIdx.x;
    int wv = tid >> 6, lane = tid & 63, c = lane & 15, quad = lane >> 4;
    int blk = blockIdx.x;
    int b = blk >> 5;                           // 32 blocks per batch
    const float4* hsrc = (const float4*)(h + (size_t)b * 128 * 72);
    for (int q = tid; q < 2304; q += 256) {
        float4 v = hsrc[q];
        *(uint2*)(&hb[q * 4]) = make_uint2(pk(v.x, v.y), pk(v.z, v.w));
    }
    if (tid < 128) ((float4*)xs)[tid] = ((const float4*)(x + (size_t)b * 512))[tid];
    __syncthreads();

    const unsigned short* W1 = wsw + W1SW;
    unsigned short* zt = ztile[wv];
    for (int p = 0; p < 4; p++) {
        size_t e0 = (size_t)blk * 512 + p * 128 + wv * 32;
        int iN[2], jN[2];
        #pragma unroll
        for (int nt = 0; nt < 2; nt++) {
            size_t e = e0 + nt * 16 + c;
            iN[nt] = ei[e]; jN[nt] = ej[e];
        }
        f32x4 acc[2][5] = {};
        #pragma unroll
        for (int kc = 0; kc < 5; kc++) {
            int ch = kc * 4 + quad;             // 8-wide k chunk, 0..19
            short8 bfr[2];
            #pragma unroll
            for (int nt = 0; nt < 2; nt++) {
                if (ch < 9) {
                    bfr[nt] = *(const short8*)(&hb[iN[nt] * 72 + ch * 8]);
                } else if (ch < 18) {
                    bfr[nt] = *(const short8*)(&hb[jN[nt] * 72 + (ch - 9) * 8]);
                } else if (ch == 18) {
                    float4 xi = *(const float4*)(&xs[iN[nt] * 4]);
                    float4 xj = *(const float4*)(&xs[jN[nt] * 4]);
                    float d0 = xi.x-xj.x, d1 = xi.y-xj.y, d2 = xi.z-xj.z, d3 = xi.w-xj.w;
                    float nrm = d0*d0 - d1*d1 - d2*d2 - d3*d3;
                    float dot = xi.x*xj.x - xi.y*xj.y - xi.z*xj.z - xi.w*xj.w;
                    unsigned u = pk(psi_f(nrm), psi_f(dot));
                    short8 t = {0,0,0,0,0,0,0,0};
                    t[0] = (short)(u & 0xffff); t[1] = (short)(u >> 16);
                    bfr[nt] = t;
                } else {
                    short8 t = {0,0,0,0,0,0,0,0};
                    bfr[nt] = t;
                }
            }
            #pragma unroll
            for (int mt = 0; mt < 5; mt++) {
                short8 w = *(const short8*)(W1 + ((kc * 5 + mt) * 64 + lane) * 8);
                acc[0][mt] = __builtin_amdgcn_mfma_f32_16x16x32_bf16(w, bfr[0], acc[0][mt], 0, 0, 0);
                acc[1][mt] = __builtin_amdgcn_mfma_f32_16x16x32_bf16(w, bfr[1], acc[1][mt], 0, 0, 0);
            }
        }
        // C -> wave tile (bf16), then coalesced global store
        #pragma unroll
        for (int nt = 0; nt < 2; nt++)
            #pragma unroll
            for (int mt = 0; mt < 5; mt++) {
                int col0 = mt * 16 + quad * 4;
                if (col0 < 72)
                    *(uint2*)(&zt[(nt * 16 + c) * 72 + col0]) =
                        make_uint2(pk(acc[nt][mt][0], acc[nt][mt][1]),
                                   pk(acc[nt][mt][2], acc[nt][mt][3]));
            }
        const uint2* ztu = (const uint2*)zt;
        uint2* zout = (uint2*)(z1bf + e0 * 72);
        #pragma unroll
        for (int it = 0; it < 9; it++) {
            int idx = it * 64 + lane;
            zout[idx] = ztu[idx];
        }
    }
}

// ---------- per-channel sum/sumsq over bf16 z1
__global__ void k_stats_bf(const unsigned* __restrict__ z1u, float* __restrict__ st)
{
    __shared__ float ssum[7][72];
    __shared__ float ssq[7][72];
    int p = threadIdx.x;      // 0..35 (col pair)
    int ty = threadIdx.y;     // 0..6
    float s0 = 0.f, s1 = 0.f, q0 = 0.f, q1 = 0.f;
    for (int r = blockIdx.x * 7 + ty; r < ROWS_E; r += gridDim.x * 7) {
        unsigned v = z1u[(size_t)r * 36 + p];
        float a = bfu2f(v & 0xffffu);
        float bb = bfu2f(v >> 16);
        s0 += a; q0 += a * a; s1 += bb; q1 += bb * bb;
    }
    ssum[ty][2*p] = s0; ssum[ty][2*p+1] = s1;
    ssq[ty][2*p] = q0;  ssq[ty][2*p+1] = q1;
    __syncthreads();
    if (ty == 0) {
        #pragma unroll
        for (int hh = 0; hh < 2; hh++) {
            int col = 2*p + hh;
            float s = 0.f, q = 0.f;
            #pragma unroll
            for (int t = 0; t < 7; t++) { s += ssum[t][col]; q += ssq[t][col]; }
            atomicAdd(&st[col], s);
            atomicAdd(&st[72 + col], q);
        }
    }
}

// ---------- per-channel sum/sumsq, fp32 rows (node path)
__global__ void k_stats(const float* __restrict__ z, int rows, float* __restrict__ st)
{
    __shared__ float ssum[4][72];
    __shared__ float ssq[4][72];
    int c = threadIdx.x, ty = threadIdx.y;
    float s = 0.f, q = 0.f;
    for (int r = blockIdx.x * 4 + ty; r < rows; r += gridDim.x * 4) {
        float v = z[(size_t)r * 72 + c];
        s += v; q += v * v;
    }
    ssum[ty][c] = s; ssq[ty][c] = q;
    __syncthreads();
    if (ty == 0) {
        s = ssum[0][c] + ssum[1][c] + ssum[2][c] + ssum[3][c];
        q = ssq[0][c] + ssq[1][c] + ssq[2][c] + ssq[3][c];
        atomicAdd(&st[c], s);
        atomicAdd(&st[72 + c], q);
    }
}

__global__ void k_finalize(float* __restrict__ st, float inv_rows,
                           const float* __restrict__ g, const float* __restrict__ b)
{
    int c = threadIdx.x;
    if (c < 72) {
        float mean = st[c] * inv_rows;
        float var  = st[72 + c] * inv_rows - mean * mean;
        float rst  = rsqrtf(var + EPS_BN);
        st[144 + c] = mean;
        st[216 + c] = rst;
        float S = rst * g[c];
        st[288 + c] = S;
        st[360 + c] = b[c] - mean * S;
    }
}

// ---------- edge main: BN->GEMM2->gate->m ; GEMM3->g2. Wave-local LDS, no barriers.
__global__ __launch_bounds__(256, 4) void k_edge_main(
    const unsigned short* __restrict__ z1bf, const float* __restrict__ st1,
    const float* __restrict__ be2, const float* __restrict__ Wm,
    const float* __restrict__ bm, const float* __restrict__ bx1,
    const float* __restrict__ Wx2, const unsigned short* __restrict__ wsw,
    float* __restrict__ m, float* __restrict__ g2out)
{
    __shared__ unsigned short tile[4][32 * 72];
    int tid = threadIdx.x;
    int wv = tid >> 6, lane = tid & 63, c = lane & 15, quad = lane >> 4;
    int blk = blockIdx.x;
    const unsigned short* W2 = wsw + W2SW;
    const unsigned short* W3 = wsw + W3SW;
    const float* Sp = st1 + 288;
    const float* Tp = st1 + 360;
    float bm0 = bm[0];
    unsigned short* tl = tile[wv];
    uint4* tl4 = (uint4*)tl;

    for (int p = 0; p < 4; p++) {
        size_t e0 = (size_t)blk * 512 + p * 128 + wv * 32;
        // stage 32 z1 rows (4.5 KB) coalesced
        const uint4* zsrc = (const uint4*)(z1bf + e0 * 72);
        tl4[lane      ] = zsrc[lane      ];
        tl4[lane +  64] = zsrc[lane +  64];
        tl4[lane + 128] = zsrc[lane + 128];
        tl4[lane + 192] = zsrc[lane + 192];
        if (lane < 32) tl4[lane + 256] = zsrc[lane + 256];

        // B-frags with fused BN+ReLU
        short8 zb[2][3];
        #pragma unroll
        for (int kc = 0; kc < 3; kc++) {
            int k0 = kc * 32 + quad * 8;
            if (k0 < 72) {
                float4 Sa = *(const float4*)(Sp + k0), Sb4 = *(const float4*)(Sp + k0 + 4);
                float4 Ta = *(const float4*)(Tp + k0), Tb4 = *(const float4*)(Tp + k0 + 4);
                #pragma unroll
                for (int nt = 0; nt < 2; nt++) {
                    uint4 u = *(const uint4*)(&tl[(nt * 16 + c) * 72 + k0]);
                    float a0 = fmaxf(bfu2f(u.x & 0xffffu)*Sa.x + Ta.x, 0.f);
                    float a1 = fmaxf(bfu2f(u.x >> 16)    *Sa.y + Ta.y, 0.f);
                    float a2 = fmaxf(bfu2f(u.y & 0xffffu)*Sa.z + Ta.z, 0.f);
                    float a3 = fmaxf(bfu2f(u.y >> 16)    *Sa.w + Ta.w, 0.f);
                    float a4 = fmaxf(bfu2f(u.z & 0xffffu)*Sb4.x + Tb4.x, 0.f);
                    float a5 = fmaxf(bfu2f(u.z >> 16)    *Sb4.y + Tb4.y, 0.f);
                    float a6 = fmaxf(bfu2f(u.w & 0xffffu)*Sb4.z + Tb4.z, 0.f);
                    float a7 = fmaxf(bfu2f(u.w >> 16)    *Sb4.w + Tb4.w, 0.f);
                    unsigned u0 = pk(a0,a1), u1 = pk(a2,a3), u2 = pk(a4,a5), u3 = pk(a6,a7);
                    short8 t;
                    t[0]=(short)(u0&0xffff); t[1]=(short)(u0>>16);
                    t[2]=(short)(u1&0xffff); t[3]=(short)(u1>>16);
                    t[4]=(short)(u2&0xffff); t[5]=(short)(u2>>16);
                    t[6]=(short)(u3&0xffff); t[7]=(short)(u3>>16);
                    zb[nt][kc] = t;
                }
            } else {
                short8 t = {0,0,0,0,0,0,0,0};
                zb[0][kc] = t; zb[1][kc] = t;
            }
        }
        // GEMM2
        f32x4 acc2[2][5] = {};
        #pragma unroll
        for (int kc = 0; kc < 3; kc++)
            #pragma unroll
            for (int mt = 0; mt < 5; mt++) {
                short8 w = *(const short8*)(W2 + ((kc * 5 + mt) * 64 + lane) * 8);
                acc2[0][mt] = __builtin_amdgcn_mfma_f32_16x16x32_bf16(w, zb[0][kc], acc2[0][mt], 0, 0, 0);
                acc2[1][mt] = __builtin_amdgcn_mfma_f32_16x16x32_bf16(w, zb[1][kc], acc2[1][mt], 0, 0, 0);
            }
        // epilogue + sigmoid gate
        float part[2] = {0.f, 0.f};
        #pragma unroll
        for (int mt = 0; mt < 5; mt++) {
            int col0 = mt * 16 + quad * 4;
            float4 be = make_float4(0,0,0,0), wm = make_float4(0,0,0,0);
            if (col0 < 72) { be = *(const float4*)(be2 + col0); wm = *(const float4*)(Wm + col0); }
            #pragma unroll
            for (int nt = 0; nt < 2; nt++) {
                float t0 = fmaxf(acc2[nt][mt][0] + be.x, 0.f);
                float t1 = fmaxf(acc2[nt][mt][1] + be.y, 0.f);
                float t2 = fmaxf(acc2[nt][mt][2] + be.z, 0.f);
                float t3 = fmaxf(acc2[nt][mt][3] + be.w, 0.f);
                acc2[nt][mt][0] = t0; acc2[nt][mt][1] = t1;
                acc2[nt][mt][2] = t2; acc2[nt][mt][3] = t3;
                part[nt] += t0*wm.x + t1*wm.y + t2*wm.z + t3*wm.w;
            }
        }
        float gate[2];
        #pragma unroll
        for (int nt = 0; nt < 2; nt++) {
            float s = part[nt];
            s += __shfl_xor(s, 16);
            s += __shfl_xor(s, 32);
            gate[nt] = 1.f / (1.f + expf(-(s + bm0)));
        }
        // m (bf16) overwrites wave tile
        #pragma unroll
        for (int nt = 0; nt < 2; nt++)
            #pragma unroll
            for (int mt = 0; mt < 5; mt++) {
                int col0 = mt * 16 + quad * 4;
                if (col0 < 72) {
                    float m0 = acc2[nt][mt][0] * gate[nt];
                    float m1 = acc2[nt][mt][1] * gate[nt];
                    float m2 = acc2[nt][mt][2] * gate[nt];
                    float m3 = acc2[nt][mt][3] * gate[nt];
                    *(uint2*)(&tl[(nt * 16 + c) * 72 + col0]) =
                        make_uint2(pk(m0, m1), pk(m2, m3));
                }
            }
        // GEMM3 from m tile
        f32x4 acc3[2][5] = {};
        #pragma unroll
        for (int kc = 0; kc < 3; kc++) {
            int k0 = kc * 32 + quad * 8;
            short8 mb[2];
            #pragma unroll
            for (int nt = 0; nt < 2; nt++) {
                if (k0 < 72) mb[nt] = *(const short8*)(&tl[(nt * 16 + c) * 72 + k0]);
                else { short8 t = {0,0,0,0,0,0,0,0}; mb[nt] = t; }
            }
            #pragma unroll
            for (int mt = 0; mt < 5; mt++) {
                short8 w = *(const short8*)(W3 + ((kc * 5 + mt) * 64 + lane) * 8);
                acc3[0][mt] = __builtin_amdgcn_mfma_f32_16x16x32_bf16(w, mb[0], acc3[0][mt], 0, 0, 0);
                acc3[1][mt] = __builtin_amdgcn_mfma_f32_16x16x32_bf16(w, mb[1], acc3[1][mt], 0, 0, 0);
            }
        }
        float part3[2] = {0.f, 0.f};
        #pragma unroll
        for (int mt = 0; mt < 5; mt++) {
            int col0 = mt * 16 + quad * 4;
            float4 bx = make_float4(0,0,0,0), wx = make_float4(0,0,0,0);
            if (col0 < 72) { bx = *(const float4*)(bx1 + col0); wx = *(const float4*)(Wx2 + col0); }
            #pragma unroll
            for (int nt = 0; nt < 2; nt++) {
                part3[nt] += fmaxf(acc3[nt][mt][0] + bx.x, 0.f) * wx.x
                           + fmaxf(acc3[nt][mt][1] + bx.y, 0.f) * wx.y
                           + fmaxf(acc3[nt][mt][2] + bx.z, 0.f) * wx.z
                           + fmaxf(acc3[nt][mt][3] + bx.w, 0.f) * wx.w;
            }
        }
        float g2v[2];
        #pragma unroll
        for (int nt = 0; nt < 2; nt++) {
            float s = part3[nt];
            s += __shfl_xor(s, 16);
            s += __shfl_xor(s, 32);
            g2v[nt] = s;
        }
        if (quad == 0) {
            g2out[e0 + c] = g2v[0];
            g2out[e0 + 16 + c] = g2v[1];
        }
        // coalesced fp32 m write-out from tile
        const uint2* tlu2 = (const uint2*)tl;
        float4* mout = (float4*)(m + e0 * 72);
        #pragma unroll
        for (int it = 0; it < 9; it++) {
            int idx = it * 64 + lane;
            uint2 v = tlu2[idx];
            mout[idx] = make_float4(bfu2f(v.x & 0xffffu), bfu2f(v.x >> 16),
                                    bfu2f(v.y & 0xffffu), bfu2f(v.y >> 16));
        }
    }
}

// ---------- xagg: segment sums of m, trans (from g2), cnt — all in LDS, then flush
__global__ __launch_bounds__(256) void k_xagg(
    const float* __restrict__ m, const float* __restrict__ x,
    const int* __restrict__ ei, const int* __restrict__ ej,
    const float* __restrict__ g2, float* __restrict__ magg,
    float* __restrict__ agg, float* __restrict__ cnt)
{
    __shared__ float ms[128 * 72];
    __shared__ float as[128 * 4];
    __shared__ float cs[128];
    __shared__ float xs[128 * 4];
    int tid = threadIdx.x;
    int b = blockIdx.x >> 4, chunk = blockIdx.x & 15;   // 512 blocks, 1024 edges each
    for (int q = tid; q < 9216; q += 256) ms[q] = 0.f;
    if (tid < 512) as[tid] = 0.f;
    if (tid < 128) cs[tid] = 0.f;
    if (tid < 128) ((float4*)xs)[tid] = ((const float4*)(x + (size_t)b * 512))[tid];
    __syncthreads();
    int wv = tid >> 6, lane = tid & 63;
    int ebase = b * 16384 + chunk * 1024;
    #pragma unroll 2
    for (int e = ebase + wv; e < ebase + 1024; e += 4) {
        int node = ei[e];
        const float* mr = m + (size_t)e * 72;
        atomicAdd(&ms[node * 72 + lane], mr[lane]);
        if (lane < 8) {
            atomicAdd(&ms[node * 72 + 64 + lane], mr[64 + lane]);
        } else if (lane < 12) {
            int l2 = lane - 8;
            int j = ej[e];
            float gv = g2[e];
            float t = fminf(fmaxf((xs[node * 4 + l2] - xs[j * 4 + l2]) * gv, -100.f), 100.f);
            atomicAdd(&as[node * 4 + l2], t);
        } else if (lane == 12) {
            atomicAdd(&cs[node], 1.f);
        }
    }
    __syncthreads();
    float* mg = magg + (size_t)b * 9216;
    for (int q = tid; q < 9216; q += 256) atomicAdd(&mg[q], ms[q]);
    if (tid < 512) atomicAdd(&agg[(size_t)b * 512 + tid], as[tid]);
    if (tid < 128) atomicAdd(&cnt[(size_t)b * 128 + tid], cs[tid]);
}

// ---------- node GEMM1: z2 = [h, magg, node_attr] @ Wh1 + bh1
__global__ __launch_bounds__(256) void k_node_gemm1(
    const float* __restrict__ h, const float* __restrict__ node_attr,
    const float* __restrict__ magg, const unsigned short* __restrict__ wsw,
    const float* __restrict__ bh1, float* __restrict__ z2)
{
    __shared__ unsigned short At[128 * 168];
    int tid = threadIdx.x;
    int rl = tid >> 1, half = tid & 1;
    size_t row = (size_t)blockIdx.x * 128 + rl;
    const float4* sp = (const float4*)((half ? magg : h) + row * 72);
    uint2* arow = (uint2*)(&At[rl * 168 + half * 72]);
    #pragma unroll
    for (int q = 0; q < 18; q++) {
        float4 v = sp[q];
        arow[q] = make_uint2(pk(v.x, v.y), pk(v.z, v.w));
    }
    if (half) {
        float4 na = *(const float4*)(node_attr + row * 4);
        *(unsigned*)(&At[rl * 168 + 144]) = pk(na.x, na.y);
        *(unsigned*)(&At[rl * 168 + 146]) = pk(na.z, na.w);
        unsigned* tailp = (unsigned*)(&At[rl * 168 + 148]);
        #pragma unroll
        for (int q = 0; q < 10; q++) tailp[q] = 0u;
    }
    __syncthreads();

    const unsigned short* WH1 = wsw + WH1SW;
    int wv = tid >> 6, lane = tid & 63, c = lane & 15, quad = lane >> 4;
    f32x4 acc[2][5] = {};
    for (int kc = 0; kc < 5; kc++) {
        int k0 = kc * 32 + quad * 8;
        short8 a0 = *(const short8*)(&At[(wv * 32 + c) * 168 + k0]);
        short8 a1 = *(const short8*)(&At[(wv * 32 + 16 + c) * 168 + k0]);
        #pragma unroll
        for (int ct = 0; ct < 5; ct++) {
            short8 bfw = *(const short8*)(WH1 + ((kc * 5 + ct) * 64 + lane) * 8);
            acc[0][ct] = __builtin_amdgcn_mfma_f32_16x16x32_bf16(a0, bfw, acc[0][ct], 0, 0, 0);
            acc[1][ct] = __builtin_amdgcn_mfma_f32_16x16x32_bf16(a1, bfw, acc[1][ct], 0, 0, 0);
        }
    }
    size_t rbase = (size_t)blockIdx.x * 128 + wv * 32 + quad * 4;
    #pragma unroll
    for (int rt = 0; rt < 2; rt++)
        #pragma unroll
        for (int ct = 0; ct < 5; ct++) {
            int col = ct * 16 + c;
            if (col < 72) {
                float bias = bh1[col];
                float* op = z2 + (rbase + rt * 16) * 72 + col;
                #pragma unroll
                for (int r = 0; r < 4; r++) op[(size_t)r * 72] = acc[rt][ct][r] + bias;
            }
        }
}

// ---------- node final: BN2+ReLU -> @Wh2 + bh2 + h ; x_out
__global__ __launch_bounds__(256) void k_node_final(
    const float* __restrict__ h, const float* __restrict__ x,
    const float* __restrict__ z2, const float* __restrict__ st2,
    const float* __restrict__ gh, const float* __restrict__ bh,
    const unsigned short* __restrict__ wsw, const float* __restrict__ bh2,
    const float* __restrict__ agg, const float* __restrict__ cnt,
    float* __restrict__ hout, float* __restrict__ xout)
{
    __shared__ unsigned short Zt[128 * 104];
    int tid = threadIdx.x;
    int rl = tid >> 1, half = tid & 1;
    size_t row = (size_t)blockIdx.x * 128 + rl;
    const float* mean = st2 + 144;
    const float* inv  = st2 + 216;
    const float4* zp = (const float4*)(z2 + row * 72) + half * 9;
    uint2* arow = (uint2*)(&Zt[rl * 104 + half * 36]);
    #pragma unroll
    for (int q = 0; q < 9; q++) {
        int k = half * 36 + q * 4;
        float4 v = zp[q];
        float a0 = fmaxf((v.x - mean[k  ]) * inv[k  ] * gh[k  ] + bh[k  ], 0.f);
        float a1 = fmaxf((v.y - mean[k+1]) * inv[k+1] * gh[k+1] + bh[k+1], 0.f);
        float a2 = fmaxf((v.z - mean[k+2]) * inv[k+2] * gh[k+2] + bh[k+2], 0.f);
        float a3 = fmaxf((v.w - mean[k+3]) * inv[k+3] * gh[k+3] + bh[k+3], 0.f);
        arow[q] = make_uint2(pk(a0, a1), pk(a2, a3));
    }
    uint2* prow = (uint2*)(&Zt[rl * 104]);
    #pragma unroll
    for (int q = 0; q < 4; q++) prow[18 + half * 4 + q] = make_uint2(0u, 0u);
    __syncthreads();

    const unsigned short* WH2 = wsw + WH2SW;
    int wv = tid >> 6, lane = tid & 63, c = lane & 15, quad = lane >> 4;
    f32x4 acc[2][5] = {};
    for (int kc = 0; kc < 3; kc++) {
        int k0 = kc * 32 + quad * 8;
        short8 a0 = *(const short8*)(&Zt[(wv * 32 + c) * 104 + k0]);
        short8 a1 = *(const short8*)(&Zt[(wv * 32 + 16 + c) * 104 + k0]);
        #pragma unroll
        for (int ct = 0; ct < 5; ct++) {
            short8 bfw = *(const short8*)(WH2 + ((kc * 5 + ct) * 64 + lane) * 8);
            acc[0][ct] = __builtin_amdgcn_mfma_f32_16x16x32_bf16(a0, bfw, acc[0][ct], 0, 0, 0);
            acc[1][ct] = __builtin_amdgcn_mfma_f32_16x16x32_bf16(a1, bfw, acc[1][ct], 0, 0, 0);
        }
    }
    size_t rbase = (size_t)blockIdx.x * 128 + wv * 32 + quad * 4;
    #pragma unroll
    for (int rt = 0; rt < 2; rt++)
        #pragma unroll
        for (int ct = 0; ct < 5; ct++) {
            int col = ct * 16 + c;
            if (col < 72) {
                float bias = bh2[col];
                #pragma unroll
                for (int r = 0; r < 4; r++) {
                    size_t gr = (rbase + rt * 16 + r);
                    hout[gr * 72 + col] = h[gr * 72 + col] + acc[rt][ct][r] + bias;
                }
            }
        }
    if (tid < 128) {
        size_t nrow = (size_t)blockIdx.x * 128 + tid;
        float cn = fmaxf(cnt[nrow], 1.f);
        float4 ag = *(const float4*)(agg + nrow * 4);
        float4 xv = *(const float4*)(x + nrow * 4);
        ((float4*)xout)[nrow] = make_float4(xv.x + ag.x / cn, xv.y + ag.y / cn,
                                            xv.z + ag.z / cn, xv.w + ag.w / cn);
    }
}

extern "C" void kernel_launch(void* const* d_in, const int* in_sizes, int n_in,
                              void* d_out, int out_size, void* d_ws, size_t ws_size,
                              hipStream_t stream)
{
    const float* h   = (const float*)d_in[0];
    const float* x   = (const float*)d_in[1];
    const int*   ei  = (const int*)d_in[2];
    const int*   ej  = (const int*)d_in[3];
    const float* na  = (const float*)d_in[4];
    const float* We1 = (const float*)d_in[5];
    const float* g1  = (const float*)d_in[6];
    const float* b1  = (const float*)d_in[7];
    const float* We2 = (const float*)d_in[8];
    const float* be2 = (const float*)d_in[9];
    const float* Wm  = (const float*)d_in[10];
    const float* bm  = (const float*)d_in[11];
    const float* Wx1 = (const float*)d_in[12];
    const float* bx1 = (const float*)d_in[13];
    const float* Wx2 = (const float*)d_in[14];
    const float* Wh1 = (const float*)d_in[15];
    const float* bh1 = (const float*)d_in[16];
    const float* gh  = (const float*)d_in[17];
    const float* bhp = (const float*)d_in[18];
    const float* Wh2 = (const float*)d_in[19];
    const float* bh2 = (const float*)d_in[20];

    float* out  = (float*)d_out;
    float* hout = out;
    float* xout = out + XOUT_OFF;
    float* m    = out + M_OFF;
    float* ws   = (float*)d_ws;
    float* st1  = ws + ST1_OFF;
    float* st2  = ws + ST2_OFF;
    float* agg  = ws + AGG_OFF;
    float* cnt  = ws + CNT_OFF;
    float* magg = ws + MAGG_OFF;
    float* z2   = ws + Z2_OFF;
    float* g2   = ws + G2_OFF;
    unsigned short* wsw  = (unsigned short*)(ws + WSW_OFF);
    unsigned short* z1bf = (unsigned short*)(ws + Z1BF_OFF);

    hipMemsetAsync(d_ws, 0, (size_t)ZERO_FLOATS * sizeof(float), stream);
    k_prep<<<(WSW_TOTAL + 255) / 256, 256, 0, stream>>>(We1, We2, Wx1, Wh1, Wh2, wsw);
    k_edge_gemm1<<<1024, 256, 0, stream>>>(h, x, ei, ej, wsw, z1bf);
    k_stats_bf<<<2048, dim3(36, 7), 0, stream>>>((const unsigned*)z1bf, st1);
    k_finalize<<<1, 128, 0, stream>>>(st1, 1.0f / (float)ROWS_E, g1, b1);
    k_edge_main<<<1024, 256, 0, stream>>>(z1bf, st1, be2, Wm, bm, bx1, Wx2, wsw, m, g2);
    k_xagg<<<512, 256, 0, stream>>>(m, x, ei, ej, g2, magg, agg, cnt);
    k_node_gemm1<<<ROWS_N / 128, 256, 0, stream>>>(h, na, magg, wsw, bh1, z2);
    k_stats<<<16, dim3(72, 4), 0, stream>>>(z2, ROWS_N, st2);
    k_finalize<<<1, 128, 0, stream>>>(st2, 1.0f / (float)ROWS_N, gh, bhp);
    k_node_final<<<ROWS_N / 128, 256, 0, stream>>>(h, x, z2, st2, gh, bhp,
                                                   wsw, bh2, agg, cnt, hout, xout);
}